// Round 1
// baseline (626.699 us; speedup 1.0000x reference)
//
#include <hip/hip_runtime.h>

#define NB 4
#define CC 512
#define NSP 4096
#define NGRP 32

using bf16x8 = __attribute__((ext_vector_type(8))) __bf16;
using f32x4  = __attribute__((ext_vector_type(4))) float;

__device__ __forceinline__ unsigned short f2bf(float f) {
  union { float f; unsigned int u; } v; v.f = f;
  unsigned int r = v.u + 0x7fffu + ((v.u >> 16) & 1u);
  return (unsigned short)(r >> 16);
}

// ---------------- weight fp32 -> bf16 ----------------
__global__ __launch_bounds__(256) void cvt_w_kernel(const float* __restrict__ wq,
    const float* __restrict__ wk, const float* __restrict__ wv,
    const float* __restrict__ wo, unsigned short* __restrict__ out) {
  int i = blockIdx.x * 256 + threadIdx.x;  // grid covers 512*512 exactly
  out[i]          = f2bf(wq[i]);
  out[i + 262144] = f2bf(wk[i]);
  out[i + 524288] = f2bf(wv[i]);
  out[i + 786432] = f2bf(wo[i]);
}

// ---------------- GroupNorm stats: one block per (b,g) ----------------
__global__ __launch_bounds__(256) void gn_stats_kernel(const float* __restrict__ x,
                                                       float* __restrict__ stats) {
  const int b = blockIdx.x >> 5, g = blockIdx.x & 31;
  const float4* p = reinterpret_cast<const float4*>(x + ((size_t)b * CC + g * 16) * NSP);
  float s = 0.f, ss = 0.f;
  for (int i = threadIdx.x; i < 16384; i += 256) {
    float4 v = p[i];
    s  += v.x + v.y + v.z + v.w;
    ss += v.x * v.x + v.y * v.y + v.z * v.z + v.w * v.w;
  }
  __shared__ float rs[4], rss[4];
  #pragma unroll
  for (int o = 32; o >= 1; o >>= 1) { s += __shfl_down(s, o); ss += __shfl_down(ss, o); }
  if ((threadIdx.x & 63) == 0) { rs[threadIdx.x >> 6] = s; rss[threadIdx.x >> 6] = ss; }
  __syncthreads();
  if (threadIdx.x == 0) {
    s = rs[0] + rs[1] + rs[2] + rs[3];
    ss = rss[0] + rss[1] + rss[2] + rss[3];
    float mean = s * (1.f / 65536.f);
    float var = ss * (1.f / 65536.f) - mean * mean;
    stats[blockIdx.x * 2 + 0] = mean;
    stats[blockIdx.x * 2 + 1] = rsqrtf(var + 1e-6f);
  }
}

// ---------------- GN apply + transpose to xnT [B][N][C] bf16 ----------------
__global__ __launch_bounds__(256) void gn_apply_kernel(const float* __restrict__ x,
    const float* __restrict__ stats, const float* __restrict__ gw,
    const float* __restrict__ gb, unsigned short* __restrict__ xnT) {
  const int b = blockIdx.z, c0 = blockIdx.y * 32, n0 = blockIdx.x * 32;
  __shared__ unsigned short tile[32][33];
  const int tx = threadIdx.x & 31, ty = threadIdx.x >> 5;
  #pragma unroll
  for (int r = 0; r < 4; ++r) {
    const int cl = ty + r * 8;
    const int c = c0 + cl;
    const int g = c >> 4;
    const float mean = stats[(b * 32 + g) * 2];
    const float rstd = stats[(b * 32 + g) * 2 + 1];
    const float sc = rstd * gw[c];
    const float sh = gb[c] - mean * sc;
    const float v = x[((size_t)b * CC + c) * NSP + n0 + tx];
    tile[cl][tx] = f2bf(v * sc + sh);
  }
  __syncthreads();
  #pragma unroll
  for (int r = 0; r < 4; ++r) {
    const int nl = ty + r * 8;
    xnT[((size_t)b * NSP + n0 + nl) * CC + c0 + tx] = tile[tx][nl];
  }
}

// ---------------- row softmax: S fp32 [4096] -> P bf16 ----------------
__global__ __launch_bounds__(256) void softmax_kernel(const float* __restrict__ S,
                                                      unsigned short* __restrict__ P) {
  const int row = blockIdx.x, t = threadIdx.x;
  const float4* p = reinterpret_cast<const float4*>(S + (size_t)row * NSP);
  float4 v[4];
  float m = -3.4e38f;
  #pragma unroll
  for (int r = 0; r < 4; ++r) {
    v[r] = p[t + r * 256];
    m = fmaxf(m, fmaxf(fmaxf(v[r].x, v[r].y), fmaxf(v[r].z, v[r].w)));
  }
  __shared__ float red[4], red2[4];
  #pragma unroll
  for (int o = 32; o >= 1; o >>= 1) m = fmaxf(m, __shfl_down(m, o));
  if ((t & 63) == 0) red[t >> 6] = m;
  __syncthreads();
  m = fmaxf(fmaxf(red[0], red[1]), fmaxf(red[2], red[3]));
  float sum = 0.f;
  #pragma unroll
  for (int r = 0; r < 4; ++r) {
    v[r].x = __expf(v[r].x - m); v[r].y = __expf(v[r].y - m);
    v[r].z = __expf(v[r].z - m); v[r].w = __expf(v[r].w - m);
    sum += v[r].x + v[r].y + v[r].z + v[r].w;
  }
  #pragma unroll
  for (int o = 32; o >= 1; o >>= 1) sum += __shfl_down(sum, o);
  if ((t & 63) == 0) red2[t >> 6] = sum;
  __syncthreads();
  sum = red2[0] + red2[1] + red2[2] + red2[3];
  const float inv = 1.0f / sum;
  ushort4* po = reinterpret_cast<ushort4*>(P + (size_t)row * NSP);
  #pragma unroll
  for (int r = 0; r < 4; ++r) {
    ushort4 o4;
    o4.x = f2bf(v[r].x * inv); o4.y = f2bf(v[r].y * inv);
    o4.z = f2bf(v[r].z * inv); o4.w = f2bf(v[r].w * inv);
    po[t + r * 256] = o4;
  }
}

// ---------------- Bt-form MFMA GEMM: C[M,N] = A[M,K] * B[N,K]^T ----------------
// BIAS: 0 none, 1 bias[row], 2 bias[col].  OBF16: bf16 out else fp32.  RESID: += resid
template<int BIAS, bool OBF16, bool RESID>
__global__ __launch_bounds__(256) void gemm_bt(
    const unsigned short* __restrict__ A, const unsigned short* __restrict__ B,
    const float* __restrict__ bias, const float* __restrict__ resid,
    void* __restrict__ Cout, int M, int N, int K, float scale,
    long long sAb, long long sBb, long long sCb, long long sRb) {
  __shared__ unsigned short sA[128 * 64];
  __shared__ unsigned short sB[128 * 64];
  const int lane = threadIdx.x & 63;
  const int wid  = threadIdx.x >> 6;
  const int bn = blockIdx.x, bm = blockIdx.y, b = blockIdx.z;
  const unsigned short* Ab = A + (size_t)b * sAb + (size_t)bm * 128 * K;
  const unsigned short* Bb = B + (size_t)b * sBb + (size_t)bn * 128 * K;
  const int wm = wid >> 1, wn = wid & 1;
  const int lrow = lane >> 3, lcol = lane & 7;

  f32x4 acc[4][4] = {};

  for (int k0 = 0; k0 < K; k0 += 64) {
    #pragma unroll
    for (int it = 0; it < 4; ++it) {
      const int stripe = wid * 4 + it;  // 8 rows per 1KB stripe
      const unsigned short* ga = Ab + (size_t)(stripe * 8 + lrow) * K + k0 + lcol * 8;
      __builtin_amdgcn_global_load_lds(
          (const __attribute__((address_space(1))) void*)ga,
          (__attribute__((address_space(3))) void*)&sA[stripe * 512], 16, 0, 0);
      const unsigned short* gb = Bb + (size_t)(stripe * 8 + lrow) * K + k0 + lcol * 8;
      __builtin_amdgcn_global_load_lds(
          (const __attribute__((address_space(1))) void*)gb,
          (__attribute__((address_space(3))) void*)&sB[stripe * 512], 16, 0, 0);
    }
    __syncthreads();
    #pragma unroll
    for (int kk = 0; kk < 2; ++kk) {
      bf16x8 af[4], bfr[4];
      #pragma unroll
      for (int m = 0; m < 4; ++m)
        af[m] = *reinterpret_cast<const bf16x8*>(
            &sA[(wm * 64 + m * 16 + (lane & 15)) * 64 + kk * 32 + (lane >> 4) * 8]);
      #pragma unroll
      for (int n = 0; n < 4; ++n)
        bfr[n] = *reinterpret_cast<const bf16x8*>(
            &sB[(wn * 64 + n * 16 + (lane & 15)) * 64 + kk * 32 + (lane >> 4) * 8]);
      #pragma unroll
      for (int m = 0; m < 4; ++m)
        #pragma unroll
        for (int n = 0; n < 4; ++n)
          acc[m][n] = __builtin_amdgcn_mfma_f32_16x16x32_bf16(af[m], bfr[n], acc[m][n], 0, 0, 0);
    }
    __syncthreads();
  }

  float* outf = (float*)Cout;
  unsigned short* outh = (unsigned short*)Cout;
  const size_t cb = (size_t)b * sCb;
  #pragma unroll
  for (int m = 0; m < 4; ++m) {
    #pragma unroll
    for (int n = 0; n < 4; ++n) {
      #pragma unroll
      for (int r = 0; r < 4; ++r) {
        const int row = bm * 128 + wm * 64 + m * 16 + (lane >> 4) * 4 + r;
        const int col = bn * 128 + wn * 64 + n * 16 + (lane & 15);
        float vv = acc[m][n][r] * scale;
        if constexpr (BIAS == 1) vv += bias[row];
        if constexpr (BIAS == 2) vv += bias[col];
        if constexpr (RESID) vv += resid[(size_t)b * sRb + (size_t)row * N + col];
        const size_t oi = cb + (size_t)row * N + col;
        if constexpr (OBF16) outh[oi] = f2bf(vv);
        else outf[oi] = vv;
      }
    }
  }
}

extern "C" void kernel_launch(void* const* d_in, const int* in_sizes, int n_in,
                              void* d_out, int out_size, void* d_ws, size_t ws_size,
                              hipStream_t stream) {
  const float* x    = (const float*)d_in[0];
  const float* gn_w = (const float*)d_in[1];
  const float* gn_b = (const float*)d_in[2];
  const float* wq   = (const float*)d_in[3];
  const float* bq   = (const float*)d_in[4];
  const float* wk   = (const float*)d_in[5];
  const float* bk   = (const float*)d_in[6];
  const float* wv   = (const float*)d_in[7];
  const float* bv   = (const float*)d_in[8];
  const float* wo   = (const float*)d_in[9];
  const float* bo   = (const float*)d_in[10];
  float* out = (float*)d_out;

  char* ws = (char*)d_ws;
  const size_t NC = (size_t)NSP * CC;           // 2M elems
  unsigned short* wq_bf = (unsigned short*)ws;  // 4 x 256K ushorts = 2 MiB
  unsigned short* wk_bf = wq_bf + 262144;
  unsigned short* wv_bf = wq_bf + 524288;
  unsigned short* wo_bf = wq_bf + 786432;
  unsigned short* xnT   = wq_bf + 1048576;      // [B][N][C] 16 MiB
  unsigned short* qT    = xnT + NB * NC;        // [B][N][C]
  unsigned short* kT    = qT + NB * NC;         // [B][N][C]
  unsigned short* vC    = kT + NB * NC;         // [B][C][N]
  unsigned short* aoutT = vC + NB * NC;         // [B][N][C]
  float* stats = (float*)(aoutT + NB * NC);     // [B*32][2]
  float* S     = (float*)((char*)stats + 1024); // [4096][4096] fp32, per-batch reuse
  unsigned short* P = (unsigned short*)(S + (size_t)NSP * NSP); // bf16

  const float scale = 0.04419417382415922f;  // 512^-0.5

  cvt_w_kernel<<<1024, 256, 0, stream>>>(wq, wk, wv, wo, wq_bf);
  gn_stats_kernel<<<NB * NGRP, 256, 0, stream>>>(x, stats);
  gn_apply_kernel<<<dim3(NSP / 32, CC / 32, NB), 256, 0, stream>>>(x, stats, gn_w, gn_b, xnT);

  // qT[i,o] = xnT . wq^T + bq   (bias per col)
  gemm_bt<2, true, false><<<dim3(CC / 128, NSP / 128, NB), 256, 0, stream>>>(
      xnT, wq_bf, bq, nullptr, qT, NSP, CC, CC, 1.0f, NC, 0, NC, 0);
  gemm_bt<2, true, false><<<dim3(CC / 128, NSP / 128, NB), 256, 0, stream>>>(
      xnT, wk_bf, bk, nullptr, kT, NSP, CC, CC, 1.0f, NC, 0, NC, 0);
  // v[o,i] = wv . xnT^T + bv    (bias per row)
  gemm_bt<1, true, false><<<dim3(NSP / 128, CC / 128, NB), 256, 0, stream>>>(
      wv_bf, xnT, bv, nullptr, vC, CC, NSP, CC, 1.0f, 0, NC, NC, 0);

  for (int b = 0; b < NB; ++b) {
    // S[i,j] = scale * qT . kT^T
    gemm_bt<0, false, false><<<dim3(NSP / 128, NSP / 128, 1), 256, 0, stream>>>(
        qT + b * NC, kT + b * NC, nullptr, nullptr, S, NSP, NSP, CC, scale, 0, 0, 0, 0);
    softmax_kernel<<<NSP, 256, 0, stream>>>(S, P);
    // aoutT[i,c] = P . v^T
    gemm_bt<0, true, false><<<dim3(CC / 128, NSP / 128, 1), 256, 0, stream>>>(
        P, vC + b * NC, nullptr, nullptr, aoutT + b * NC, NSP, CC, NSP, 1.0f, 0, 0, 0, 0);
  }

  // out[o,i] = wo . aoutT^T + bo + x   (fp32, residual fused)
  gemm_bt<1, false, true><<<dim3(NSP / 128, CC / 128, NB), 256, 0, stream>>>(
      wo_bf, aoutT, bo, x, out, CC, NSP, CC, 1.0f, 0, NC, NC, NC);
}

// Round 2
// 373.358 us; speedup vs baseline: 1.6785x; 1.6785x over previous
//
#include <hip/hip_runtime.h>

#define NB 4
#define CC 512
#define NSP 4096
#define NGRP 32

using bf16x8 = __attribute__((ext_vector_type(8))) __bf16;
using f32x4  = __attribute__((ext_vector_type(4))) float;

__device__ __forceinline__ unsigned short f2bf(float f) {
  union { float f; unsigned int u; } v; v.f = f;
  unsigned int r = v.u + 0x7fffu + ((v.u >> 16) & 1u);
  return (unsigned short)(r >> 16);
}

__device__ __forceinline__ float bf2f(unsigned short h) {
  union { unsigned int u; float f; } v; v.u = ((unsigned int)h) << 16;
  return v.f;
}

// ---------------- weight fp32 -> bf16 ----------------
__global__ __launch_bounds__(256) void cvt_w_kernel(const float* __restrict__ wq,
    const float* __restrict__ wk, const float* __restrict__ wv,
    const float* __restrict__ wo, unsigned short* __restrict__ out) {
  int i = blockIdx.x * 256 + threadIdx.x;  // grid covers 512*512 exactly
  out[i]          = f2bf(wq[i]);
  out[i + 262144] = f2bf(wk[i]);
  out[i + 524288] = f2bf(wv[i]);
  out[i + 786432] = f2bf(wo[i]);
}

// ---------------- GroupNorm stats: one block per (b,g) ----------------
__global__ __launch_bounds__(256) void gn_stats_kernel(const float* __restrict__ x,
                                                       float* __restrict__ stats) {
  const int b = blockIdx.x >> 5, g = blockIdx.x & 31;
  const float4* p = reinterpret_cast<const float4*>(x + ((size_t)b * CC + g * 16) * NSP);
  float s = 0.f, ss = 0.f;
  for (int i = threadIdx.x; i < 16384; i += 256) {
    float4 v = p[i];
    s  += v.x + v.y + v.z + v.w;
    ss += v.x * v.x + v.y * v.y + v.z * v.z + v.w * v.w;
  }
  __shared__ float rs[4], rss[4];
  #pragma unroll
  for (int o = 32; o >= 1; o >>= 1) { s += __shfl_down(s, o); ss += __shfl_down(ss, o); }
  if ((threadIdx.x & 63) == 0) { rs[threadIdx.x >> 6] = s; rss[threadIdx.x >> 6] = ss; }
  __syncthreads();
  if (threadIdx.x == 0) {
    s = rs[0] + rs[1] + rs[2] + rs[3];
    ss = rss[0] + rss[1] + rss[2] + rss[3];
    float mean = s * (1.f / 65536.f);
    float var = ss * (1.f / 65536.f) - mean * mean;
    stats[blockIdx.x * 2 + 0] = mean;
    stats[blockIdx.x * 2 + 1] = rsqrtf(var + 1e-6f);
  }
}

// ---------------- GN apply + transpose to xnT [B][N][C] bf16 ----------------
__global__ __launch_bounds__(256) void gn_apply_kernel(const float* __restrict__ x,
    const float* __restrict__ stats, const float* __restrict__ gw,
    const float* __restrict__ gb, unsigned short* __restrict__ xnT) {
  const int b = blockIdx.z, c0 = blockIdx.y * 32, n0 = blockIdx.x * 32;
  __shared__ unsigned short tile[32][33];
  const int tx = threadIdx.x & 31, ty = threadIdx.x >> 5;
  #pragma unroll
  for (int r = 0; r < 4; ++r) {
    const int cl = ty + r * 8;
    const int c = c0 + cl;
    const int g = c >> 4;
    const float mean = stats[(b * 32 + g) * 2];
    const float rstd = stats[(b * 32 + g) * 2 + 1];
    const float sc = rstd * gw[c];
    const float sh = gb[c] - mean * sc;
    const float v = x[((size_t)b * CC + c) * NSP + n0 + tx];
    tile[cl][tx] = f2bf(v * sc + sh);
  }
  __syncthreads();
  #pragma unroll
  for (int r = 0; r < 4; ++r) {
    const int nl = ty + r * 8;
    xnT[((size_t)b * NSP + n0 + nl) * CC + c0 + tx] = tile[tx][nl];
  }
}

// ---------------- row softmax, bf16 in-place: S row [4096] ----------------
__global__ __launch_bounds__(256) void softmax_bf16_kernel(unsigned short* __restrict__ S) {
  const size_t row = blockIdx.x;
  const int t = threadIdx.x;
  uint4* pv = reinterpret_cast<uint4*>(S + row * NSP);
  uint4 a[2];
  a[0] = pv[t];
  a[1] = pv[t + 256];
  float v[16];
  #pragma unroll
  for (int r = 0; r < 2; ++r) {
    const unsigned int* w = reinterpret_cast<const unsigned int*>(&a[r]);
    #pragma unroll
    for (int j = 0; j < 4; ++j) {
      v[r * 8 + j * 2]     = bf2f((unsigned short)(w[j] & 0xffffu));
      v[r * 8 + j * 2 + 1] = bf2f((unsigned short)(w[j] >> 16));
    }
  }
  float m = -3.4e38f;
  #pragma unroll
  for (int i = 0; i < 16; ++i) m = fmaxf(m, v[i]);
  __shared__ float red[4], red2[4];
  #pragma unroll
  for (int o = 32; o >= 1; o >>= 1) m = fmaxf(m, __shfl_down(m, o));
  if ((t & 63) == 0) red[t >> 6] = m;
  __syncthreads();
  m = fmaxf(fmaxf(red[0], red[1]), fmaxf(red[2], red[3]));
  float sum = 0.f;
  #pragma unroll
  for (int i = 0; i < 16; ++i) { v[i] = __expf(v[i] - m); sum += v[i]; }
  #pragma unroll
  for (int o = 32; o >= 1; o >>= 1) sum += __shfl_down(sum, o);
  if ((t & 63) == 0) red2[t >> 6] = sum;
  __syncthreads();
  sum = red2[0] + red2[1] + red2[2] + red2[3];
  const float inv = 1.0f / sum;
  #pragma unroll
  for (int r = 0; r < 2; ++r) {
    unsigned int* w = reinterpret_cast<unsigned int*>(&a[r]);
    #pragma unroll
    for (int j = 0; j < 4; ++j) {
      unsigned int lo = f2bf(v[r * 8 + j * 2] * inv);
      unsigned int hi = f2bf(v[r * 8 + j * 2 + 1] * inv);
      w[j] = lo | (hi << 16);
    }
  }
  pv[t] = a[0];
  pv[t + 256] = a[1];
}

// ---------------- Bt-form MFMA GEMM: C[M,N] = A[M,K] * B[N,K]^T ----------------
// BIAS: 0 none, 1 bias[row], 2 bias[col].  OBF16: bf16 out else fp32.  RESID: += resid
template<int BIAS, bool OBF16, bool RESID>
__global__ __launch_bounds__(256) void gemm_bt(
    const unsigned short* __restrict__ A, const unsigned short* __restrict__ B,
    const float* __restrict__ bias, const float* __restrict__ resid,
    void* __restrict__ Cout, int M, int N, int K, float scale,
    long long sAb, long long sBb, long long sCb, long long sRb) {
  __shared__ unsigned short sA[128 * 64];
  __shared__ unsigned short sB[128 * 64];
  const int lane = threadIdx.x & 63;
  const int wid  = threadIdx.x >> 6;
  const int bn = blockIdx.x, bm = blockIdx.y, b = blockIdx.z;
  const unsigned short* Ab = A + (size_t)b * sAb + (size_t)bm * 128 * K;
  const unsigned short* Bb = B + (size_t)b * sBb + (size_t)bn * 128 * K;
  const int wm = wid >> 1, wn = wid & 1;
  const int lrow = lane >> 3, lcol = lane & 7;

  f32x4 acc[4][4] = {};

  for (int k0 = 0; k0 < K; k0 += 64) {
    #pragma unroll
    for (int it = 0; it < 4; ++it) {
      const int stripe = wid * 4 + it;  // 8 rows per 1KB stripe
      const unsigned short* ga = Ab + (size_t)(stripe * 8 + lrow) * K + k0 + lcol * 8;
      __builtin_amdgcn_global_load_lds(
          (const __attribute__((address_space(1))) void*)ga,
          (__attribute__((address_space(3))) void*)&sA[stripe * 512], 16, 0, 0);
      const unsigned short* gb = Bb + (size_t)(stripe * 8 + lrow) * K + k0 + lcol * 8;
      __builtin_amdgcn_global_load_lds(
          (const __attribute__((address_space(1))) void*)gb,
          (__attribute__((address_space(3))) void*)&sB[stripe * 512], 16, 0, 0);
    }
    __syncthreads();
    #pragma unroll
    for (int kk = 0; kk < 2; ++kk) {
      bf16x8 af[4], bfr[4];
      #pragma unroll
      for (int m = 0; m < 4; ++m)
        af[m] = *reinterpret_cast<const bf16x8*>(
            &sA[(wm * 64 + m * 16 + (lane & 15)) * 64 + kk * 32 + (lane >> 4) * 8]);
      #pragma unroll
      for (int n = 0; n < 4; ++n)
        bfr[n] = *reinterpret_cast<const bf16x8*>(
            &sB[(wn * 64 + n * 16 + (lane & 15)) * 64 + kk * 32 + (lane >> 4) * 8]);
      #pragma unroll
      for (int m = 0; m < 4; ++m)
        #pragma unroll
        for (int n = 0; n < 4; ++n)
          acc[m][n] = __builtin_amdgcn_mfma_f32_16x16x32_bf16(af[m], bfr[n], acc[m][n], 0, 0, 0);
    }
    __syncthreads();
  }

  float* outf = (float*)Cout;
  unsigned short* outh = (unsigned short*)Cout;
  const size_t cb = (size_t)b * sCb;
  #pragma unroll
  for (int m = 0; m < 4; ++m) {
    #pragma unroll
    for (int n = 0; n < 4; ++n) {
      #pragma unroll
      for (int r = 0; r < 4; ++r) {
        const int row = bm * 128 + wm * 64 + m * 16 + (lane >> 4) * 4 + r;
        const int col = bn * 128 + wn * 64 + n * 16 + (lane & 15);
        float vv = acc[m][n][r] * scale;
        if constexpr (BIAS == 1) vv += bias[row];
        if constexpr (BIAS == 2) vv += bias[col];
        if constexpr (RESID) vv += resid[(size_t)b * sRb + (size_t)row * N + col];
        const size_t oi = cb + (size_t)row * N + col;
        if constexpr (OBF16) outh[oi] = f2bf(vv);
        else outf[oi] = vv;
      }
    }
  }
}

extern "C" void kernel_launch(void* const* d_in, const int* in_sizes, int n_in,
                              void* d_out, int out_size, void* d_ws, size_t ws_size,
                              hipStream_t stream) {
  const float* x    = (const float*)d_in[0];
  const float* gn_w = (const float*)d_in[1];
  const float* gn_b = (const float*)d_in[2];
  const float* wq   = (const float*)d_in[3];
  const float* bq   = (const float*)d_in[4];
  const float* wk   = (const float*)d_in[5];
  const float* bk   = (const float*)d_in[6];
  const float* wv   = (const float*)d_in[7];
  const float* bv   = (const float*)d_in[8];
  const float* wo   = (const float*)d_in[9];
  const float* bo   = (const float*)d_in[10];
  float* out = (float*)d_out;

  char* ws = (char*)d_ws;
  const size_t NC = (size_t)NSP * CC;           // 2M elems
  unsigned short* wq_bf = (unsigned short*)ws;  // 4 x 256K ushorts = 2 MiB
  unsigned short* wk_bf = wq_bf + 262144;
  unsigned short* wv_bf = wq_bf + 524288;
  unsigned short* wo_bf = wq_bf + 786432;
  unsigned short* xnT   = wq_bf + 1048576;      // [B][N][C] 16 MiB
  unsigned short* qT    = xnT + NB * NC;        // [B][N][C]
  unsigned short* kT    = qT + NB * NC;         // [B][N][C]
  unsigned short* vC    = kT + NB * NC;         // [B][C][N]
  unsigned short* aoutT = vC + NB * NC;         // [B][N][C]
  float* stats = (float*)(aoutT + NB * NC);     // [B*32][2]
  unsigned short* S = (unsigned short*)((char*)stats + 1024); // bf16 S/P in-place

  const float scale = 0.04419417382415922f;  // 512^-0.5
  const size_t SS = (size_t)NSP * NSP;       // elems per batch of S
  // bytes: weights+activations 85,983,232 + stats 1024 + batched S 134,217,728
  const bool batched = ws_size >= 220300000ull;

  cvt_w_kernel<<<1024, 256, 0, stream>>>(wq, wk, wv, wo, wq_bf);
  gn_stats_kernel<<<NB * NGRP, 256, 0, stream>>>(x, stats);
  gn_apply_kernel<<<dim3(NSP / 32, CC / 32, NB), 256, 0, stream>>>(x, stats, gn_w, gn_b, xnT);

  // qT[i,o] = xnT . wq^T + bq   (bias per col)
  gemm_bt<2, true, false><<<dim3(CC / 128, NSP / 128, NB), 256, 0, stream>>>(
      xnT, wq_bf, bq, nullptr, qT, NSP, CC, CC, 1.0f, NC, 0, NC, 0);
  gemm_bt<2, true, false><<<dim3(CC / 128, NSP / 128, NB), 256, 0, stream>>>(
      xnT, wk_bf, bk, nullptr, kT, NSP, CC, CC, 1.0f, NC, 0, NC, 0);
  // v[o,i] = wv . xnT^T + bv    (bias per row)
  gemm_bt<1, true, false><<<dim3(NSP / 128, CC / 128, NB), 256, 0, stream>>>(
      wv_bf, xnT, bv, nullptr, vC, CC, NSP, CC, 1.0f, 0, NC, NC, 0);

  if (batched) {
    // S[b,i,j] = scale * qT . kT^T  (bf16)
    gemm_bt<0, true, false><<<dim3(NSP / 128, NSP / 128, NB), 256, 0, stream>>>(
        qT, kT, nullptr, nullptr, S, NSP, NSP, CC, scale, NC, NC, (long long)SS, 0);
    softmax_bf16_kernel<<<NB * NSP, 256, 0, stream>>>(S);
    // aoutT[b,i,c] = P . v^T
    gemm_bt<0, true, false><<<dim3(CC / 128, NSP / 128, NB), 256, 0, stream>>>(
        S, vC, nullptr, nullptr, aoutT, NSP, CC, NSP, 1.0f, (long long)SS, NC, NC, 0);
  } else {
    for (int b = 0; b < NB; ++b) {
      gemm_bt<0, true, false><<<dim3(NSP / 128, NSP / 128, 1), 256, 0, stream>>>(
          qT + b * NC, kT + b * NC, nullptr, nullptr, S, NSP, NSP, CC, scale, 0, 0, 0, 0);
      softmax_bf16_kernel<<<NSP, 256, 0, stream>>>(S);
      gemm_bt<0, true, false><<<dim3(CC / 128, NSP / 128, 1), 256, 0, stream>>>(
          S, vC + b * NC, nullptr, nullptr, aoutT + b * NC, NSP, CC, NSP, 1.0f, 0, 0, 0, 0);
    }
  }

  // out[o,i] = wo . aoutT^T + bo + x   (fp32, residual fused)
  gemm_bt<1, false, true><<<dim3(NSP / 128, CC / 128, NB), 256, 0, stream>>>(
      wo_bf, aoutT, bo, x, out, CC, NSP, CC, 1.0f, 0, NC, NC, NC);
}